// Round 15
// baseline (157.182 us; speedup 1.0000x reference)
//
#include <hip/hip_runtime.h>

using bf16 = __bf16;
typedef __bf16 bf16x2 __attribute__((ext_vector_type(2)));
typedef __bf16 bf16x4v __attribute__((ext_vector_type(4)));
typedef __bf16 bf16x8 __attribute__((ext_vector_type(8)));
typedef float f32x4 __attribute__((ext_vector_type(4)));
typedef float floatx4 __attribute__((ext_vector_type(4)));

#define MFMA16(a, b, c) __builtin_amdgcn_mfma_f32_16x16x32_bf16((a), (b), (c), 0, 0, 0)

__device__ __forceinline__ float exp2a(float x) {
  float r;
  asm("v_exp_f32 %0, %1" : "=v"(r) : "v"(x));
  return r;
}

// ---- fused cast fp32->bf16 (x, w_qkv, w_out) + RoPE cos/sin table build ----
__global__ __launch_bounds__(256) void cast3_kernel(const float* __restrict__ a,
                                                    const float* __restrict__ b,
                                                    const float* __restrict__ c,
                                                    bf16* __restrict__ oa,
                                                    bf16* __restrict__ ob,
                                                    bf16* __restrict__ oc,
                                                    const int* __restrict__ pos,
                                                    float2* __restrict__ tab) {
  int i = blockIdx.x * 256 + threadIdx.x;  // [0, 2097152)
  if (i < 65536) {  // rope table: 2048 pos x 32 freqs
    int s = i >> 5, ip = i & 31;
    float freq = exp2f(-(float)ip * (13.287712379549449f / 32.0f));
    float ang = (float)pos[s] * freq;
    float sn, cs;
    sincosf(ang, &sn, &cs);
    tab[i] = make_float2(cs, sn);
  }
  const float* in;
  bf16* out;
  int off;
  if (i < 1048576) {
    in = a; out = oa; off = i;
  } else if (i < 1835008) {
    in = b; out = ob; off = i - 1048576;
  } else {
    in = c; out = oc; off = i - 1835008;
  }
  floatx4 v = *(const floatx4*)(in + (size_t)off * 4);
  bf16x4v o;
  #pragma unroll
  for (int j = 0; j < 4; ++j) o[j] = (bf16)v[j];
  *(bf16x4v*)(out + (size_t)off * 4) = o;
}

// ---- GEMM: C[M][N] = A[M][K] * B[N][K]^T (+ optional fused table-RoPE) ----
template <bool OUT_F32, bool ROPE>
__global__ __launch_bounds__(256, 2) void gemm_bt(const bf16* __restrict__ A,
                                                  const bf16* __restrict__ B,
                                                  void* __restrict__ Cv,
                                                  int M, int N, int K,
                                                  const float2* __restrict__ tab) {
  __shared__ bf16 As[128 * 32];
  __shared__ bf16 Bs[128 * 32];
  const int t = threadIdx.x;
  const int l = t & 63;
  const int w = t >> 6;
  const int m0 = blockIdx.y * 128;
  const int n0 = blockIdx.x * 128;
  const int wr = (w >> 1) * 64;
  const int wc = (w & 1) * 64;
  const int lr = l & 15;
  const int lk = (l >> 4) * 8;

  f32x4 acc[4][4] = {};

  const int srow = t >> 2;
  const int scol = (t & 3) * 8;

  for (int k0 = 0; k0 < K; k0 += 32) {
    __syncthreads();
    #pragma unroll
    for (int j = 0; j < 2; ++j) {
      const bf16* ga = A + (size_t)(m0 + j * 64 + srow) * K + k0 + scol;
      __builtin_amdgcn_global_load_lds(
          (const __attribute__((address_space(1))) void*)ga,
          (__attribute__((address_space(3))) void*)(As + (j * 64 + srow) * 32 + scol),
          16, 0, 0);
      const bf16* gb = B + (size_t)(n0 + j * 64 + srow) * K + k0 + scol;
      __builtin_amdgcn_global_load_lds(
          (const __attribute__((address_space(1))) void*)gb,
          (__attribute__((address_space(3))) void*)(Bs + (j * 64 + srow) * 32 + scol),
          16, 0, 0);
    }
    __syncthreads();
    bf16x8 af[4], bfr[4];
    #pragma unroll
    for (int i = 0; i < 4; ++i) af[i] = *(const bf16x8*)(As + (wr + i * 16 + lr) * 32 + lk);
    #pragma unroll
    for (int i = 0; i < 4; ++i) bfr[i] = *(const bf16x8*)(Bs + (wc + i * 16 + lr) * 32 + lk);
    #pragma unroll
    for (int i = 0; i < 4; ++i)
      #pragma unroll
      for (int j = 0; j < 4; ++j)
        acc[i][j] = MFMA16(af[i], bfr[j], acc[i][j]);
  }

  const int cr0 = (l >> 4) * 4;
  const int cc = l & 15;

  if constexpr (ROPE) {
    if (n0 < 2048) {  // q or k block (block-uniform)
      int ip[4];
      #pragma unroll
      for (int j = 0; j < 4; ++j) ip[j] = ((n0 + wc + j * 16 + cc) & 63) >> 1;
      const float sgn = (cc & 1) ? 1.f : -1.f;
      #pragma unroll
      for (int i = 0; i < 4; ++i) {
        #pragma unroll
        for (int r = 0; r < 4; ++r) {
          int row = m0 + wr + i * 16 + cr0 + r;
          int s = row & 2047;
          #pragma unroll
          for (int j = 0; j < 4; ++j) {
            float2 cs = tab[s * 32 + ip[j]];
            float self = acc[i][j][r];
            float partner = __shfl_xor(self, 1, 64);
            acc[i][j][r] = self * cs.x + sgn * cs.y * partner;
          }
        }
      }
    }
  }

  #pragma unroll
  for (int i = 0; i < 4; ++i) {
    #pragma unroll
    for (int j = 0; j < 4; ++j) {
      int row = m0 + wr + i * 16 + cr0;
      int col = n0 + wc + j * 16 + cc;
      #pragma unroll
      for (int r = 0; r < 4; ++r) {
        if constexpr (OUT_F32)
          ((float*)Cv)[(size_t)(row + r) * N + col] = acc[i][j][r];
        else
          ((bf16*)Cv)[(size_t)(row + r) * N + col] = (bf16)acc[i][j][r];
      }
    }
  }
}

// ---- causal flash attention v14: K-split x2, single-buffered K/V (16 KB) ----
// grid (32 bh, 32 qt, 2 z), 256 thr = 4 waves; wave w owns q rows [q0+16w, q0+16w+16).
// z processes kt = z, z+2, ... -> 2048 blocks, 8 blocks/CU resident = 8 waves/SIMD.
// Writes normalized partial O (bf16, attn layout) + (m,l); combine merges in-place.
// Core per tile = v11: zero-shuffle PV, lane-local exp2 softmax, defer-max, XCD pin.
__global__ __launch_bounds__(256, 8) void fa_causal(const bf16* __restrict__ qkv,
                                                    bf16* __restrict__ part0,
                                                    bf16* __restrict__ part1,
                                                    float2* __restrict__ ml) {
  const int bh = blockIdx.x;
  const int b = bh >> 4, h = bh & 15;
  const int qt = 31 - (int)blockIdx.y;  // heavy blocks first within each XCD
  const int q0 = qt * 64;
  const int z = blockIdx.z;
  const int t = threadIdx.x, w = t >> 6, l = t & 63;
  const int lq = l & 15;
  const int g = l >> 4;
  const int lk = g * 8;
  const int swz = lq & 7;
  const int hz = lq >> 3;

  __shared__ bf16 SH[2][64 * 64];  // SH[0] = K, SH[1] = V^T; 16 KB total; epilogue reuse

  const size_t rs = 3072;
  const bf16* Qg = qkv + (size_t)(b * 2048) * rs + h * 64;
  const bf16* Kg = Qg + 1024;
  const bf16* Vg = Qg + 2048;

  const int qrow0 = q0 + w * 16;
  const int qg = qrow0 + lq;

  const float SC = 0.125f * 1.44269504088896f;  // scale * log2(e), folded into Q
  bf16x8 qfr[2];
  #pragma unroll
  for (int kk = 0; kk < 2; ++kk) {
    bf16x8 qv = *(const bf16x8*)(Qg + (size_t)qg * rs + kk * 32 + lk);
    #pragma unroll
    for (int j = 0; j < 8; ++j) qv[j] = (bf16)((float)qv[j] * SC);
    qfr[kk] = qv;
  }

  f32x4 o[4] = {};
  float mrow = -1e30f, lrow = 0.f;

  const int nkt = qt + 1;
  const int krow_in = l >> 3;            // 0..7
  const int kcsrc = (l & 7) ^ krow_in;   // pre-swizzled source chunk
  const int kp = t >> 3;                 // 0..31 key pair
  const int K0 = kp * 2;
  const int cd = t & 7;                  // d chunk 0..7
  const int slot0 = (K0 & 32) | (((K0 >> 2) & 3) << 3) | (((K0 >> 4) & 1) << 2) | (K0 & 3);

  bf16x8 va, vb2;

  #define STAGE_K(KT)                                                                   \
    {                                                                                   \
      _Pragma("unroll")                                                                 \
      for (int c = 0; c < 2; ++c) {                                                     \
        const int rowbase = w * 8 + c * 32;                                             \
        const bf16* src = Kg + (size_t)((KT)*64 + rowbase + krow_in) * rs + kcsrc * 8;  \
        __builtin_amdgcn_global_load_lds(                                               \
            (const __attribute__((address_space(1))) void*)src,                         \
            (__attribute__((address_space(3))) void*)(&SH[0][rowbase * 64]), 16, 0, 0); \
      }                                                                                 \
    }
  #define LOAD_V(KT)                                                          \
    {                                                                         \
      const bf16* vsrc = Vg + (size_t)((KT)*64 + K0) * rs + cd * 8;           \
      va = *(const bf16x8*)(vsrc);                                            \
      vb2 = *(const bf16x8*)(vsrc + rs);                                      \
    }
  #define WRITE_V()                                                           \
    {                                                                         \
      _Pragma("unroll")                                                       \
      for (int e = 0; e < 8; ++e) {                                           \
        bf16x2 pr;                                                            \
        pr[0] = va[e];                                                        \
        pr[1] = vb2[e];                                                       \
        *(bf16x2*)(&SH[1][(cd * 8 + e) * 64 + (slot0 ^ ((e ^ cd) << 3))]) = pr; \
      }                                                                       \
    }

  for (int kt = z; kt < nkt; kt += 2) {
    if (kt != z) __syncthreads();  // all waves done reading previous tile
    STAGE_K(kt)
    LOAD_V(kt)
    WRITE_V()
    __syncthreads();               // staged K (gll drained) + V visible

    if (kt * 64 <= qrow0 + 15) {   // wave-uniform causal skip
      const bf16* Kc = SH[0];
      const bf16* Vc = SH[1];
      const bool fullw = (kt * 64 + 63 <= qrow0);

      f32x4 sc[4] = {};
      __builtin_amdgcn_s_setprio(1);
      #pragma unroll
      for (int kf = 0; kf < 4; ++kf) {
        const int krow = kf * 16 + lq;
        bf16x8 kb0 = *(const bf16x8*)(&Kc[krow * 64 + ((0 + g) ^ swz) * 8]);
        bf16x8 kb1 = *(const bf16x8*)(&Kc[krow * 64 + ((4 + g) ^ swz) * 8]);
        sc[kf] = MFMA16(kb0, qfr[0], sc[kf]);
        sc[kf] = MFMA16(kb1, qfr[1], sc[kf]);
      }
      __builtin_amdgcn_s_setprio(0);

      float pv[16];
      if (fullw) {
        #pragma unroll
        for (int i = 0; i < 16; ++i) pv[i] = sc[i >> 2][i & 3];
      } else {
        #pragma unroll
        for (int kf = 0; kf < 4; ++kf)
          #pragma unroll
          for (int r = 0; r < 4; ++r) {
            int key = kt * 64 + kf * 16 + g * 4 + r;
            pv[kf * 4 + r] = (key <= qg) ? sc[kf][r] : -1e30f;
          }
      }
      // balanced max tree
      float m0_ = fmaxf(pv[0], pv[1]), m1_ = fmaxf(pv[2], pv[3]);
      float m2_ = fmaxf(pv[4], pv[5]), m3_ = fmaxf(pv[6], pv[7]);
      float m4_ = fmaxf(pv[8], pv[9]), m5_ = fmaxf(pv[10], pv[11]);
      float m6_ = fmaxf(pv[12], pv[13]), m7_ = fmaxf(pv[14], pv[15]);
      float ma = fmaxf(fmaxf(m0_, m1_), fmaxf(m2_, m3_));
      float mb = fmaxf(fmaxf(m4_, m5_), fmaxf(m6_, m7_));
      float mxl = fmaxf(ma, mb);
      if (!__all(mxl <= mrow)) {  // defer-max
        float mx = fmaxf(mxl, __shfl_xor(mxl, 16, 64));
        mx = fmaxf(mx, __shfl_xor(mx, 32, 64));
        float mnew = fmaxf(mrow, mx);
        float al = exp2a(mrow - mnew);
        lrow *= al;
        #pragma unroll
        for (int fd = 0; fd < 4; ++fd)
          #pragma unroll
          for (int r = 0; r < 4; ++r) o[fd][r] *= al;
        mrow = mnew;
      }
      #pragma unroll
      for (int i = 0; i < 16; ++i) pv[i] = exp2a(pv[i] - mrow);
      // balanced sum tree
      float s0_ = pv[0] + pv[1], s1_ = pv[2] + pv[3];
      float s2_ = pv[4] + pv[5], s3_ = pv[6] + pv[7];
      float s4_ = pv[8] + pv[9], s5_ = pv[10] + pv[11];
      float s6_ = pv[12] + pv[13], s7_ = pv[14] + pv[15];
      float rsum = ((s0_ + s1_) + (s2_ + s3_)) + ((s4_ + s5_) + (s6_ + s7_));
      rsum += __shfl_xor(rsum, 16, 64);
      rsum += __shfl_xor(rsum, 32, 64);
      lrow += rsum;

      bf16x8 p0, p1;
      #pragma unroll
      for (int i = 0; i < 8; ++i) {
        p0[i] = (bf16)pv[i];
        p1[i] = (bf16)pv[8 + i];
      }

      __builtin_amdgcn_s_setprio(1);
      #pragma unroll
      for (int fd = 0; fd < 4; ++fd) {
        const int drow = fd * 16 + lq;
        {
          int pc = (0 * 4 + g) ^ swz ^ (fd << 1) ^ hz;
          bf16x8 vb = *(const bf16x8*)(&Vc[drow * 64 + pc * 8]);
          o[fd] = MFMA16(vb, p0, o[fd]);
        }
        {
          int pc = (1 * 4 + g) ^ swz ^ (fd << 1) ^ hz;
          bf16x8 vb = *(const bf16x8*)(&Vc[drow * 64 + pc * 8]);
          o[fd] = MFMA16(vb, p1, o[fd]);
        }
      }
      __builtin_amdgcn_s_setprio(0);
    }
  }

  // ---- epilogue: normalized partial O -> attn layout, plus (m,l) per q-row ----
  __syncthreads();  // all waves done with SH
  bf16* Obase = (z == 0) ? part0 : part1;
  bf16* Os = (bf16*)SH + w * (16 * 72);  // 4 x 2304 B = 9216 B < 16 KB
  float inv = (lrow > 0.f) ? 1.0f / lrow : 0.f;
  #pragma unroll
  for (int fd = 0; fd < 4; ++fd) {
    bf16x4v ov;
    #pragma unroll
    for (int r = 0; r < 4; ++r) ov[r] = (bf16)(o[fd][r] * inv);
    *(bf16x4v*)(&Os[lq * 72 + fd * 16 + g * 4]) = ov;
  }
  if (g == 0)
    ml[((size_t)z * 32 + bh) * 2048 + qrow0 + lq] = make_float2(mrow, lrow);
  asm volatile("" ::: "memory");
  #pragma unroll
  for (int p = 0; p < 2; ++p) {
    int idx = p * 64 + l;
    int row16 = idx >> 3, c8 = idx & 7;
    bf16x8 v = *(const bf16x8*)(&Os[row16 * 72 + c8 * 8]);
    *(bf16x8*)(&Obase[(size_t)(b * 2048 + qrow0 + row16) * 1024 + h * 64 + c8 * 8]) = v;
  }
}

// ---- combine: attn = merge(part0, part1), in place over part1 ----
__global__ __launch_bounds__(256) void combine_kernel(const bf16* __restrict__ p0,
                                                      bf16* __restrict__ p1out,
                                                      const float2* __restrict__ ml) {
  int i = blockIdx.x * 256 + threadIdx.x;  // 1,048,576 threads x 4 elems
  size_t e4 = (size_t)i * 4;
  int row = (int)(e4 >> 10), col = (int)(e4 & 1023);
  int bhq = ((row >> 11) * 16 + (col >> 6)) * 2048 + (row & 2047);
  float2 a0 = ml[bhq];
  float2 a1 = ml[65536 + bhq];
  float m = fmaxf(a0.x, a1.x);
  float w0 = exp2a(a0.x - m) * a0.y;
  float w1 = exp2a(a1.x - m) * a1.y;
  float inv = 1.0f / (w0 + w1);
  w0 *= inv;
  w1 *= inv;
  bf16x4v v0 = *(const bf16x4v*)(p0 + e4);
  bf16x4v v1 = *(const bf16x4v*)(p1out + e4);
  bf16x4v ov;
  #pragma unroll
  for (int j = 0; j < 4; ++j) ov[j] = (bf16)((float)v0[j] * w0 + (float)v1[j] * w1);
  *(bf16x4v*)(p1out + e4) = ov;
}

// ---------------- launch ----------------
extern "C" void kernel_launch(void* const* d_in, const int* in_sizes, int n_in,
                              void* d_out, int out_size, void* d_ws, size_t ws_size,
                              hipStream_t stream) {
  const float* x = (const float*)d_in[0];
  const int* pos = (const int*)d_in[1];
  const float* w_qkv = (const float*)d_in[2];
  const float* w_out = (const float*)d_in[3];
  float* out = (float*)d_out;

  char* ws = (char*)d_ws;
  bf16* xb   = (bf16*)(ws);                 // 8 MB; reused as part0 after gemm1
  bf16* wqb  = (bf16*)(ws + (8u << 20));    // 6 MB; reused as ml after gemm1
  bf16* wob  = (bf16*)(ws + (14u << 20));   // 2 MB
  bf16* qkv  = (bf16*)(ws + (16u << 20));   // 24 MB
  bf16* attn = (bf16*)(ws + (40u << 20));   // 8 MB; part1 -> merged attn in place
  float2* tab = (float2*)(ws + (40u << 20));  // 512 KB; dead before fa writes part1
  bf16* part0 = xb;
  float2* mlb = (float2*)wqb;

  cast3_kernel<<<8192, 256, 0, stream>>>(x, w_qkv, w_out, xb, wqb, wob, pos, tab);

  dim3 g1(3072 / 128, 4096 / 128);
  gemm_bt<false, true><<<g1, 256, 0, stream>>>(xb, wqb, (void*)qkv, 4096, 3072, 1024, tab);

  dim3 gfa(32, 32, 2);  // x = bh (XCD pin), y = qt (reversed), z = K-split
  fa_causal<<<gfa, 256, 0, stream>>>(qkv, part0, attn, mlb);

  combine_kernel<<<4096, 256, 0, stream>>>(part0, attn, mlb);

  dim3 g2(1024 / 128, 4096 / 128);
  gemm_bt<true, false><<<g2, 256, 0, stream>>>(attn, wob, (void*)out, 4096, 1024, 1024, nullptr);
}

// Round 16
// 115.422 us; speedup vs baseline: 1.3618x; 1.3618x over previous
//
#include <hip/hip_runtime.h>

using bf16 = __bf16;
typedef __bf16 bf16x2 __attribute__((ext_vector_type(2)));
typedef __bf16 bf16x4v __attribute__((ext_vector_type(4)));
typedef __bf16 bf16x8 __attribute__((ext_vector_type(8)));
typedef float f32x4 __attribute__((ext_vector_type(4)));
typedef float floatx4 __attribute__((ext_vector_type(4)));

#define MFMA16(a, b, c) __builtin_amdgcn_mfma_f32_16x16x32_bf16((a), (b), (c), 0, 0, 0)

__device__ __forceinline__ float exp2a(float x) {
  float r;
  asm("v_exp_f32 %0, %1" : "=v"(r) : "v"(x));
  return r;
}

// ---- fused cast fp32 -> bf16 for x, w_qkv, w_out (one launch) ----
__global__ __launch_bounds__(256) void cast3_kernel(const float* __restrict__ a,
                                                    const float* __restrict__ b,
                                                    const float* __restrict__ c,
                                                    bf16* __restrict__ oa,
                                                    bf16* __restrict__ ob,
                                                    bf16* __restrict__ oc) {
  int i = blockIdx.x * 256 + threadIdx.x;  // [0, 2097152)
  const float* in;
  bf16* out;
  int off;
  if (i < 1048576) {
    in = a; out = oa; off = i;
  } else if (i < 1835008) {
    in = b; out = ob; off = i - 1048576;
  } else {
    in = c; out = oc; off = i - 1835008;
  }
  floatx4 v = *(const floatx4*)(in + (size_t)off * 4);
  bf16x4v o;
  #pragma unroll
  for (int j = 0; j < 4; ++j) o[j] = (bf16)v[j];
  *(bf16x4v*)(out + (size_t)off * 4) = o;
}

// ---- GEMM: C[M][N] = A[M][K] * B[N][K]^T (+ optional fused RoPE), XCD-chunked swizzle ----
template <bool OUT_F32, bool ROPE>
__global__ __launch_bounds__(256, 2) void gemm_bt(const bf16* __restrict__ A,
                                                  const bf16* __restrict__ B,
                                                  void* __restrict__ Cv,
                                                  int M, int N, int K,
                                                  const int* __restrict__ pos) {
  __shared__ bf16 As[128 * 32];
  __shared__ bf16 Bs[128 * 32];
  const int t = threadIdx.x;
  const int l = t & 63;
  const int w = t >> 6;
  // T1: XCD-chunked remap (requires nwg % 8 == 0; 768 and 256 both qualify)
  const int nwgx = gridDim.x;
  const int orig = blockIdx.y * nwgx + blockIdx.x;
  const int cpx = (nwgx * gridDim.y) >> 3;
  const int wgid = (orig & 7) * cpx + (orig >> 3);
  const int m0 = (wgid / nwgx) * 128;
  const int n0 = (wgid % nwgx) * 128;
  const int wr = (w >> 1) * 64;
  const int wc = (w & 1) * 64;
  const int lr = l & 15;
  const int lk = (l >> 4) * 8;

  f32x4 acc[4][4] = {};

  const int srow = t >> 2;
  const int scol = (t & 3) * 8;

  for (int k0 = 0; k0 < K; k0 += 32) {
    __syncthreads();
    #pragma unroll
    for (int j = 0; j < 2; ++j) {
      const bf16* ga = A + (size_t)(m0 + j * 64 + srow) * K + k0 + scol;
      __builtin_amdgcn_global_load_lds(
          (const __attribute__((address_space(1))) void*)ga,
          (__attribute__((address_space(3))) void*)(As + (j * 64 + srow) * 32 + scol),
          16, 0, 0);
      const bf16* gb = B + (size_t)(n0 + j * 64 + srow) * K + k0 + scol;
      __builtin_amdgcn_global_load_lds(
          (const __attribute__((address_space(1))) void*)gb,
          (__attribute__((address_space(3))) void*)(Bs + (j * 64 + srow) * 32 + scol),
          16, 0, 0);
    }
    __syncthreads();
    bf16x8 af[4], bfr[4];
    #pragma unroll
    for (int i = 0; i < 4; ++i) af[i] = *(const bf16x8*)(As + (wr + i * 16 + lr) * 32 + lk);
    #pragma unroll
    for (int i = 0; i < 4; ++i) bfr[i] = *(const bf16x8*)(Bs + (wc + i * 16 + lr) * 32 + lk);
    #pragma unroll
    for (int i = 0; i < 4; ++i)
      #pragma unroll
      for (int j = 0; j < 4; ++j)
        acc[i][j] = MFMA16(af[i], bfr[j], acc[i][j]);
  }

  const int cr0 = (l >> 4) * 4;
  const int cc = l & 15;

  if constexpr (ROPE) {
    if (n0 < 2048) {  // q or k block (block-uniform)
      const float L2T32 = 13.287712379549449f / 32.0f;     // log2(theta)/32
      const float INV2PI = 0.15915494309189535f;
      float frev[4];
      #pragma unroll
      for (int j = 0; j < 4; ++j) {
        int col = n0 + wc + j * 16 + cc;
        int ip = (col & 63) >> 1;
        frev[j] = exp2f(-(float)ip * L2T32) * INV2PI;      // freq / 2pi
      }
      const float sgn = (cc & 1) ? 1.f : -1.f;
      #pragma unroll
      for (int i = 0; i < 4; ++i) {
        #pragma unroll
        for (int r = 0; r < 4; ++r) {
          int row = m0 + wr + i * 16 + cr0 + r;
          float p = (float)pos[row & 2047];
          #pragma unroll
          for (int j = 0; j < 4; ++j) {
            float self = acc[i][j][r];
            float partner = __shfl_xor(self, 1, 64);
            float ang = p * frev[j];
            float fr = ang - floorf(ang);
            float sn, cs;
            asm("v_sin_f32 %0, %1" : "=v"(sn) : "v"(fr));  // sin(2*pi*fr)
            asm("v_cos_f32 %0, %1" : "=v"(cs) : "v"(fr));
            acc[i][j][r] = self * cs + sgn * sn * partner;
          }
        }
      }
    }
  }

  #pragma unroll
  for (int i = 0; i < 4; ++i) {
    #pragma unroll
    for (int j = 0; j < 4; ++j) {
      int row = m0 + wr + i * 16 + cr0;
      int col = n0 + wc + j * 16 + cc;
      #pragma unroll
      for (int r = 0; r < 4; ++r) {
        if constexpr (OUT_F32)
          ((float*)Cv)[(size_t)(row + r) * N + col] = acc[i][j][r];
        else
          ((bf16*)Cv)[(size_t)(row + r) * N + col] = (bf16)acc[i][j][r];
      }
    }
  }
}

// ---- causal flash attention v11 (round-12 proven core; lrow update moved after PV) ----
// grid (32 bh, 32 qt): XCD = bh%8 (K/V L2-pinned); q0 reversed (heavy first).
// 256 thr = 4 waves; wave w owns q rows [q0+16w, q0+16w+16). KV tile 64, K+V dbuf.
// SC folded into Q; lane-local defer-max; zero-shuffle PV via key-slot permutation.
__global__ __launch_bounds__(256, 4) void fa_causal(const bf16* __restrict__ qkv,
                                                    bf16* __restrict__ attn) {
  const int bh = blockIdx.x;
  const int b = bh >> 4, h = bh & 15;
  const int q0 = ((int)gridDim.y - 1 - (int)blockIdx.y) * 64;
  const int t = threadIdx.x, w = t >> 6, l = t & 63;
  const int lq = l & 15;
  const int g = l >> 4;
  const int lk = g * 8;
  const int swz = lq & 7;
  const int hz = lq >> 3;

  __shared__ bf16 Ks[2][64 * 64];   // K dbuf, source-XOR swizzled; epilogue reuse
  __shared__ bf16 Vt[2][64 * 64];   // V^T dbuf, slot-permuted + XOR swizzled

  const size_t rs = 3072;
  const bf16* Qg = qkv + (size_t)(b * 2048) * rs + h * 64;
  const bf16* Kg = Qg + 1024;
  const bf16* Vg = Qg + 2048;

  const int qrow0 = q0 + w * 16;
  const int qg = qrow0 + lq;

  const float SC = 0.125f * 1.44269504088896f;  // scale * log2(e), folded into Q
  bf16x8 qfr[2];
  #pragma unroll
  for (int kk = 0; kk < 2; ++kk) {
    bf16x8 qv = *(const bf16x8*)(Qg + (size_t)qg * rs + kk * 32 + lk);
    #pragma unroll
    for (int j = 0; j < 8; ++j) qv[j] = (bf16)((float)qv[j] * SC);
    qfr[kk] = qv;
  }

  f32x4 o[4] = {};
  float mrow = -1e30f, lrow = 0.f;

  const int nkt = (q0 + 64) >> 6;
  const int krow_in = l >> 3;            // 0..7
  const int kcsrc = (l & 7) ^ krow_in;   // pre-swizzled source chunk
  const int kp = t >> 3;                 // 0..31 key pair
  const int K0 = kp * 2;
  const int cd = t & 7;                  // d chunk 0..7
  const int slot0 = (K0 & 32) | (((K0 >> 2) & 3) << 3) | (((K0 >> 4) & 1) << 2) | (K0 & 3);

  bf16x8 va, vb2;

  #define STAGE_K(KT, BUF)                                                                \
    {                                                                                     \
      _Pragma("unroll")                                                                   \
      for (int c = 0; c < 2; ++c) {                                                       \
        const int rowbase = w * 8 + c * 32;                                               \
        const bf16* src = Kg + (size_t)((KT)*64 + rowbase + krow_in) * rs + kcsrc * 8;    \
        __builtin_amdgcn_global_load_lds(                                                 \
            (const __attribute__((address_space(1))) void*)src,                           \
            (__attribute__((address_space(3))) void*)(&Ks[BUF][rowbase * 64]), 16, 0, 0); \
      }                                                                                   \
    }
  #define LOAD_V(KT)                                                          \
    {                                                                         \
      const bf16* vsrc = Vg + (size_t)((KT)*64 + K0) * rs + cd * 8;           \
      va = *(const bf16x8*)(vsrc);                                            \
      vb2 = *(const bf16x8*)(vsrc + rs);                                      \
    }
  #define WRITE_V(BUF)                                                        \
    {                                                                         \
      _Pragma("unroll")                                                       \
      for (int e = 0; e < 8; ++e) {                                           \
        bf16x2 pr;                                                            \
        pr[0] = va[e];                                                        \
        pr[1] = vb2[e];                                                       \
        *(bf16x2*)(&Vt[BUF][(cd * 8 + e) * 64 + (slot0 ^ ((e ^ cd) << 3))]) = pr; \
      }                                                                       \
    }

  STAGE_K(0, 0)
  LOAD_V(0)
  WRITE_V(0)
  __syncthreads();

  for (int kt = 0; kt < nkt; ++kt) {
    const bool pf = (kt + 1 < nkt);
    if (pf) {
      LOAD_V(kt + 1)
      STAGE_K(kt + 1, (kt + 1) & 1)
    }

    if (kt * 64 <= qrow0 + 15) {  // wave-uniform causal skip
      const bf16* Kc = Ks[kt & 1];
      const bf16* Vc = Vt[kt & 1];
      const bool fullw = (kt * 64 + 63 <= qrow0);

      f32x4 sc[4] = {};
      __builtin_amdgcn_s_setprio(1);
      #pragma unroll
      for (int kf = 0; kf < 4; ++kf) {
        const int krow = kf * 16 + lq;
        bf16x8 kb0 = *(const bf16x8*)(&Kc[krow * 64 + ((0 + g) ^ swz) * 8]);
        bf16x8 kb1 = *(const bf16x8*)(&Kc[krow * 64 + ((4 + g) ^ swz) * 8]);
        sc[kf] = MFMA16(kb0, qfr[0], sc[kf]);
        sc[kf] = MFMA16(kb1, qfr[1], sc[kf]);
      }
      __builtin_amdgcn_s_setprio(0);

      float pv[16];
      if (fullw) {
        #pragma unroll
        for (int i = 0; i < 16; ++i) pv[i] = sc[i >> 2][i & 3];
      } else {
        #pragma unroll
        for (int kf = 0; kf < 4; ++kf)
          #pragma unroll
          for (int r = 0; r < 4; ++r) {
            int key = kt * 64 + kf * 16 + g * 4 + r;
            pv[kf * 4 + r] = (key <= qg) ? sc[kf][r] : -1e30f;
          }
      }
      // lane-local max (max3-fusable)
      float mxl = fmaxf(fmaxf(pv[0], pv[1]), pv[2]);
      mxl = fmaxf(fmaxf(mxl, pv[3]), pv[4]);
      mxl = fmaxf(fmaxf(mxl, pv[5]), pv[6]);
      mxl = fmaxf(fmaxf(mxl, pv[7]), pv[8]);
      mxl = fmaxf(fmaxf(mxl, pv[9]), pv[10]);
      mxl = fmaxf(fmaxf(mxl, pv[11]), pv[12]);
      mxl = fmaxf(fmaxf(mxl, pv[13]), pv[14]);
      mxl = fmaxf(mxl, pv[15]);
      if (!__all(mxl <= mrow)) {  // defer-max: reduce+rescale only when max grew
        float mx = fmaxf(mxl, __shfl_xor(mxl, 16, 64));
        mx = fmaxf(mx, __shfl_xor(mx, 32, 64));
        float mnew = fmaxf(mrow, mx);
        float al = exp2a(mrow - mnew);
        lrow *= al;
        #pragma unroll
        for (int fd = 0; fd < 4; ++fd)
          #pragma unroll
          for (int r = 0; r < 4; ++r) o[fd][r] *= al;
        mrow = mnew;
      }
      #pragma unroll
      for (int i = 0; i < 16; ++i) pv[i] = exp2a(pv[i] - mrow);

      // zero-shuffle B-frags; PV issued BEFORE the lrow cross-lane reduce
      bf16x8 p0, p1;
      #pragma unroll
      for (int i = 0; i < 8; ++i) {
        p0[i] = (bf16)pv[i];
        p1[i] = (bf16)pv[8 + i];
      }

      __builtin_amdgcn_s_setprio(1);
      #pragma unroll
      for (int fd = 0; fd < 4; ++fd) {
        const int drow = fd * 16 + lq;
        {
          int pc = (0 * 4 + g) ^ swz ^ (fd << 1) ^ hz;
          bf16x8 vb = *(const bf16x8*)(&Vc[drow * 64 + pc * 8]);
          o[fd] = MFMA16(vb, p0, o[fd]);
        }
        {
          int pc = (1 * 4 + g) ^ swz ^ (fd << 1) ^ hz;
          bf16x8 vb = *(const bf16x8*)(&Vc[drow * 64 + pc * 8]);
          o[fd] = MFMA16(vb, p1, o[fd]);
        }
      }
      __builtin_amdgcn_s_setprio(0);

      // lrow update off the PV critical path
      float rsum = ((pv[0] + pv[1]) + (pv[2] + pv[3])) + ((pv[4] + pv[5]) + (pv[6] + pv[7]));
      rsum += ((pv[8] + pv[9]) + (pv[10] + pv[11])) + ((pv[12] + pv[13]) + (pv[14] + pv[15]));
      rsum += __shfl_xor(rsum, 16, 64);
      rsum += __shfl_xor(rsum, 32, 64);
      lrow += rsum;
    }

    if (pf) {
      WRITE_V((kt + 1) & 1)  // other buffer: safe before barrier
      __syncthreads();       // publishes V stores + K gll for tile kt+1
    }
  }

  // ---- epilogue: O^T -> [q][d] via LDS (reuse Ks) -> coalesced b128 stores ----
  __syncthreads();  // all waves done reading K/V
  bf16* Os = (bf16*)Ks + w * (16 * 72);
  float inv = 1.0f / lrow;
  #pragma unroll
  for (int fd = 0; fd < 4; ++fd) {
    bf16x4v ov;
    #pragma unroll
    for (int r = 0; r < 4; ++r) ov[r] = (bf16)(o[fd][r] * inv);
    *(bf16x4v*)(&Os[lq * 72 + fd * 16 + g * 4]) = ov;
  }
  asm volatile("" ::: "memory");
  #pragma unroll
  for (int p = 0; p < 2; ++p) {
    int idx = p * 64 + l;
    int row16 = idx >> 3, c8 = idx & 7;
    bf16x8 v = *(const bf16x8*)(&Os[row16 * 72 + c8 * 8]);
    *(bf16x8*)(&attn[(size_t)(b * 2048 + qrow0 + row16) * 1024 + h * 64 + c8 * 8]) = v;
  }
}

// ---------------- launch ----------------
extern "C" void kernel_launch(void* const* d_in, const int* in_sizes, int n_in,
                              void* d_out, int out_size, void* d_ws, size_t ws_size,
                              hipStream_t stream) {
  const float* x = (const float*)d_in[0];
  const int* pos = (const int*)d_in[1];
  const float* w_qkv = (const float*)d_in[2];
  const float* w_out = (const float*)d_in[3];
  float* out = (float*)d_out;

  char* ws = (char*)d_ws;
  bf16* xb   = (bf16*)(ws);
  bf16* wqb  = (bf16*)(ws + (8u << 20));
  bf16* wob  = (bf16*)(ws + (14u << 20));
  bf16* qkv  = (bf16*)(ws + (16u << 20));
  bf16* attn = (bf16*)(ws + (40u << 20));

  cast3_kernel<<<8192, 256, 0, stream>>>(x, w_qkv, w_out, xb, wqb, wob);

  dim3 g1(3072 / 128, 4096 / 128);
  gemm_bt<false, true><<<g1, 256, 0, stream>>>(xb, wqb, (void*)qkv, 4096, 3072, 1024, pos);

  dim3 gfa(32, 2048 / 64);  // x = bh (XCD pin), y = q-tile (reversed in kernel)
  fa_causal<<<gfa, 256, 0, stream>>>(qkv, attn);

  dim3 g2(1024 / 128, 4096 / 128);
  gemm_bt<true, false><<<g2, 256, 0, stream>>>(attn, wob, (void*)out, 4096, 1024, 1024, nullptr);
}

// Round 17
// 114.525 us; speedup vs baseline: 1.3725x; 1.0078x over previous
//
#include <hip/hip_runtime.h>

using bf16 = __bf16;
typedef __bf16 bf16x2 __attribute__((ext_vector_type(2)));
typedef __bf16 bf16x4v __attribute__((ext_vector_type(4)));
typedef __bf16 bf16x8 __attribute__((ext_vector_type(8)));
typedef float f32x4 __attribute__((ext_vector_type(4)));
typedef float floatx4 __attribute__((ext_vector_type(4)));

#define MFMA16(a, b, c) __builtin_amdgcn_mfma_f32_16x16x32_bf16((a), (b), (c), 0, 0, 0)

__device__ __forceinline__ float exp2a(float x) {
  float r;
  asm("v_exp_f32 %0, %1" : "=v"(r) : "v"(x));
  return r;
}

// ---------------- fused cast fp32 -> bf16 for x, w_qkv, w_out (one launch) ----------------
__global__ __launch_bounds__(256) void cast3_kernel(const float* __restrict__ a,
                                                    const float* __restrict__ b,
                                                    const float* __restrict__ c,
                                                    bf16* __restrict__ oa,
                                                    bf16* __restrict__ ob,
                                                    bf16* __restrict__ oc) {
  int i = blockIdx.x * 256 + threadIdx.x;  // [0, 2097152)
  const float* in;
  bf16* out;
  int off;
  if (i < 1048576) {               // x: 4M elems
    in = a; out = oa; off = i;
  } else if (i < 1835008) {        // w_qkv: 3M elems
    in = b; out = ob; off = i - 1048576;
  } else {                         // w_out: 1M elems
    in = c; out = oc; off = i - 1835008;
  }
  floatx4 v = *(const floatx4*)(in + (size_t)off * 4);
  bf16x4v o;
  #pragma unroll
  for (int j = 0; j < 4; ++j) o[j] = (bf16)v[j];
  *(bf16x4v*)(out + (size_t)off * 4) = o;
}

// ---------------- GEMM: C[M][N] = A[M][K] * B[N][K]^T (+ optional fused RoPE) ----------
// ROPE: applied to output cols < 2048 (q,k) -- block-uniform since n0 % 128 == 0.
// Pair partner col^1 lives in lane cc^1 (shfl_xor 1). Trig: v_sin/v_cos (revolutions).
template <bool OUT_F32, bool ROPE>
__global__ __launch_bounds__(256, 2) void gemm_bt(const bf16* __restrict__ A,
                                                  const bf16* __restrict__ B,
                                                  void* __restrict__ Cv,
                                                  int M, int N, int K,
                                                  const int* __restrict__ pos) {
  __shared__ bf16 As[128 * 32];
  __shared__ bf16 Bs[128 * 32];
  const int t = threadIdx.x;
  const int l = t & 63;
  const int w = t >> 6;
  const int m0 = blockIdx.y * 128;
  const int n0 = blockIdx.x * 128;
  const int wr = (w >> 1) * 64;
  const int wc = (w & 1) * 64;
  const int lr = l & 15;
  const int lk = (l >> 4) * 8;

  f32x4 acc[4][4] = {};

  const int srow = t >> 2;
  const int scol = (t & 3) * 8;

  for (int k0 = 0; k0 < K; k0 += 32) {
    __syncthreads();
    #pragma unroll
    for (int j = 0; j < 2; ++j) {
      const bf16* ga = A + (size_t)(m0 + j * 64 + srow) * K + k0 + scol;
      __builtin_amdgcn_global_load_lds(
          (const __attribute__((address_space(1))) void*)ga,
          (__attribute__((address_space(3))) void*)(As + (j * 64 + srow) * 32 + scol),
          16, 0, 0);
      const bf16* gb = B + (size_t)(n0 + j * 64 + srow) * K + k0 + scol;
      __builtin_amdgcn_global_load_lds(
          (const __attribute__((address_space(1))) void*)gb,
          (__attribute__((address_space(3))) void*)(Bs + (j * 64 + srow) * 32 + scol),
          16, 0, 0);
    }
    __syncthreads();
    bf16x8 af[4], bfr[4];
    #pragma unroll
    for (int i = 0; i < 4; ++i) af[i] = *(const bf16x8*)(As + (wr + i * 16 + lr) * 32 + lk);
    #pragma unroll
    for (int i = 0; i < 4; ++i) bfr[i] = *(const bf16x8*)(Bs + (wc + i * 16 + lr) * 32 + lk);
    #pragma unroll
    for (int i = 0; i < 4; ++i)
      #pragma unroll
      for (int j = 0; j < 4; ++j)
        acc[i][j] = MFMA16(af[i], bfr[j], acc[i][j]);
  }

  const int cr0 = (l >> 4) * 4;
  const int cc = l & 15;

  if constexpr (ROPE) {
    if (n0 < 2048) {  // q or k block (block-uniform)
      const float L2T32 = 13.287712379549449f / 32.0f;     // log2(theta)/32
      const float INV2PI = 0.15915494309189535f;
      float frev[4];
      #pragma unroll
      for (int j = 0; j < 4; ++j) {
        int col = n0 + wc + j * 16 + cc;
        int ip = (col & 63) >> 1;
        frev[j] = exp2f(-(float)ip * L2T32) * INV2PI;      // freq / 2pi
      }
      const float sgn = (cc & 1) ? 1.f : -1.f;
      #pragma unroll
      for (int i = 0; i < 4; ++i) {
        #pragma unroll
        for (int r = 0; r < 4; ++r) {
          int row = m0 + wr + i * 16 + cr0 + r;
          float p = (float)pos[row & 2047];
          #pragma unroll
          for (int j = 0; j < 4; ++j) {
            float self = acc[i][j][r];
            float partner = __shfl_xor(self, 1, 64);
            float ang = p * frev[j];
            float fr = ang - floorf(ang);
            float sn, cs;
            asm("v_sin_f32 %0, %1" : "=v"(sn) : "v"(fr));  // sin(2*pi*fr)
            asm("v_cos_f32 %0, %1" : "=v"(cs) : "v"(fr));
            acc[i][j][r] = self * cs + sgn * sn * partner;
          }
        }
      }
    }
  }

  #pragma unroll
  for (int i = 0; i < 4; ++i) {
    #pragma unroll
    for (int j = 0; j < 4; ++j) {
      int row = m0 + wr + i * 16 + cr0;
      int col = n0 + wc + j * 16 + cc;
      #pragma unroll
      for (int r = 0; r < 4; ++r) {
        if constexpr (OUT_F32)
          ((float*)Cv)[(size_t)(row + r) * N + col] = acc[i][j][r];
        else
          ((bf16*)Cv)[(size_t)(row + r) * N + col] = (bf16)acc[i][j][r];
      }
    }
  }
}

// ---------------- causal flash attention v11 (round-12 proven best) ----------------
// grid (32 bh, 32 qt): XCD = bh%8 (K/V L2-pinned); q0 reversed (heavy first).
// 256 thr = 4 waves; wave w owns q rows [q0+16w, q0+16w+16). KV tile 64, K+V dbuf.
// SC folded into Q; lane-local defer-max; zero-shuffle PV via key-slot permutation.
__global__ __launch_bounds__(256, 4) void fa_causal(const bf16* __restrict__ qkv,
                                                    bf16* __restrict__ attn) {
  const int bh = blockIdx.x;
  const int b = bh >> 4, h = bh & 15;
  const int q0 = ((int)gridDim.y - 1 - (int)blockIdx.y) * 64;
  const int t = threadIdx.x, w = t >> 6, l = t & 63;
  const int lq = l & 15;
  const int g = l >> 4;
  const int lk = g * 8;
  const int swz = lq & 7;
  const int hz = lq >> 3;

  __shared__ bf16 Ks[2][64 * 64];   // K dbuf, source-XOR swizzled; epilogue reuse
  __shared__ bf16 Vt[2][64 * 64];   // V^T dbuf, slot-permuted + XOR swizzled

  const size_t rs = 3072;
  const bf16* Qg = qkv + (size_t)(b * 2048) * rs + h * 64;
  const bf16* Kg = Qg + 1024;
  const bf16* Vg = Qg + 2048;

  const int qrow0 = q0 + w * 16;
  const int qg = qrow0 + lq;

  const float SC = 0.125f * 1.44269504088896f;  // scale * log2(e), folded into Q
  bf16x8 qfr[2];
  #pragma unroll
  for (int kk = 0; kk < 2; ++kk) {
    bf16x8 qv = *(const bf16x8*)(Qg + (size_t)qg * rs + kk * 32 + lk);
    #pragma unroll
    for (int j = 0; j < 8; ++j) qv[j] = (bf16)((float)qv[j] * SC);
    qfr[kk] = qv;
  }

  f32x4 o[4] = {};
  float mrow = -1e30f, lrow = 0.f;

  const int nkt = (q0 + 64) >> 6;
  const int krow_in = l >> 3;            // 0..7
  const int kcsrc = (l & 7) ^ krow_in;   // pre-swizzled source chunk
  const int kp = t >> 3;                 // 0..31 key pair
  const int K0 = kp * 2;
  const int cd = t & 7;                  // d chunk 0..7
  const int slot0 = (K0 & 32) | (((K0 >> 2) & 3) << 3) | (((K0 >> 4) & 1) << 2) | (K0 & 3);

  bf16x8 va, vb2;

  #define STAGE_K(KT, BUF)                                                                \
    {                                                                                     \
      _Pragma("unroll")                                                                   \
      for (int c = 0; c < 2; ++c) {                                                       \
        const int rowbase = w * 8 + c * 32;                                               \
        const bf16* src = Kg + (size_t)((KT)*64 + rowbase + krow_in) * rs + kcsrc * 8;    \
        __builtin_amdgcn_global_load_lds(                                                 \
            (const __attribute__((address_space(1))) void*)src,                           \
            (__attribute__((address_space(3))) void*)(&Ks[BUF][rowbase * 64]), 16, 0, 0); \
      }                                                                                   \
    }
  #define LOAD_V(KT)                                                          \
    {                                                                         \
      const bf16* vsrc = Vg + (size_t)((KT)*64 + K0) * rs + cd * 8;           \
      va = *(const bf16x8*)(vsrc);                                            \
      vb2 = *(const bf16x8*)(vsrc + rs);                                      \
    }
  #define WRITE_V(BUF)                                                        \
    {                                                                         \
      _Pragma("unroll")                                                       \
      for (int e = 0; e < 8; ++e) {                                           \
        bf16x2 pr;                                                            \
        pr[0] = va[e];                                                        \
        pr[1] = vb2[e];                                                       \
        *(bf16x2*)(&Vt[BUF][(cd * 8 + e) * 64 + (slot0 ^ ((e ^ cd) << 3))]) = pr; \
      }                                                                       \
    }

  STAGE_K(0, 0)
  LOAD_V(0)
  WRITE_V(0)
  __syncthreads();

  for (int kt = 0; kt < nkt; ++kt) {
    const bool pf = (kt + 1 < nkt);
    if (pf) {
      LOAD_V(kt + 1)
      STAGE_K(kt + 1, (kt + 1) & 1)
    }

    if (kt * 64 <= qrow0 + 15) {  // wave-uniform causal skip
      const bf16* Kc = Ks[kt & 1];
      const bf16* Vc = Vt[kt & 1];
      const bool fullw = (kt * 64 + 63 <= qrow0);

      f32x4 sc[4] = {};
      __builtin_amdgcn_s_setprio(1);
      #pragma unroll
      for (int kf = 0; kf < 4; ++kf) {
        const int krow = kf * 16 + lq;
        bf16x8 kb0 = *(const bf16x8*)(&Kc[krow * 64 + ((0 + g) ^ swz) * 8]);
        bf16x8 kb1 = *(const bf16x8*)(&Kc[krow * 64 + ((4 + g) ^ swz) * 8]);
        sc[kf] = MFMA16(kb0, qfr[0], sc[kf]);
        sc[kf] = MFMA16(kb1, qfr[1], sc[kf]);
      }
      __builtin_amdgcn_s_setprio(0);

      float pv[16];
      if (fullw) {
        #pragma unroll
        for (int i = 0; i < 16; ++i) pv[i] = sc[i >> 2][i & 3];
      } else {
        #pragma unroll
        for (int kf = 0; kf < 4; ++kf)
          #pragma unroll
          for (int r = 0; r < 4; ++r) {
            int key = kt * 64 + kf * 16 + g * 4 + r;
            pv[kf * 4 + r] = (key <= qg) ? sc[kf][r] : -1e30f;
          }
      }
      // max3-shaped lane-local max (8 ops with v_max3 fusion)
      float mxl = fmaxf(fmaxf(pv[0], pv[1]), pv[2]);
      mxl = fmaxf(fmaxf(mxl, pv[3]), pv[4]);
      mxl = fmaxf(fmaxf(mxl, pv[5]), pv[6]);
      mxl = fmaxf(fmaxf(mxl, pv[7]), pv[8]);
      mxl = fmaxf(fmaxf(mxl, pv[9]), pv[10]);
      mxl = fmaxf(fmaxf(mxl, pv[11]), pv[12]);
      mxl = fmaxf(fmaxf(mxl, pv[13]), pv[14]);
      mxl = fmaxf(mxl, pv[15]);
      // lane-local defer-max check: shfl-reduce only when some row max grew
      if (!__all(mxl <= mrow)) {
        float mx = fmaxf(mxl, __shfl_xor(mxl, 16, 64));
        mx = fmaxf(mx, __shfl_xor(mx, 32, 64));
        float mnew = fmaxf(mrow, mx);
        float al = exp2a(mrow - mnew);
        lrow *= al;
        #pragma unroll
        for (int fd = 0; fd < 4; ++fd)
          #pragma unroll
          for (int r = 0; r < 4; ++r) o[fd][r] *= al;
        mrow = mnew;
      }
      float rsum = 0.f;
      #pragma unroll
      for (int i = 0; i < 16; ++i) {
        float p = exp2a(pv[i] - mrow);
        pv[i] = p;
        rsum += p;
      }
      rsum += __shfl_xor(rsum, 16, 64);
      rsum += __shfl_xor(rsum, 32, 64);
      lrow += rsum;

      // zero-shuffle B-frags (slot permutation absorbs the relayout)
      bf16x8 p0, p1;
      #pragma unroll
      for (int i = 0; i < 8; ++i) {
        p0[i] = (bf16)pv[i];
        p1[i] = (bf16)pv[8 + i];
      }

      __builtin_amdgcn_s_setprio(1);
      #pragma unroll
      for (int fd = 0; fd < 4; ++fd) {
        const int drow = fd * 16 + lq;
        {
          int pc = (0 * 4 + g) ^ swz ^ (fd << 1) ^ hz;
          bf16x8 vb = *(const bf16x8*)(&Vc[drow * 64 + pc * 8]);
          o[fd] = MFMA16(vb, p0, o[fd]);
        }
        {
          int pc = (1 * 4 + g) ^ swz ^ (fd << 1) ^ hz;
          bf16x8 vb = *(const bf16x8*)(&Vc[drow * 64 + pc * 8]);
          o[fd] = MFMA16(vb, p1, o[fd]);
        }
      }
      __builtin_amdgcn_s_setprio(0);
    }

    if (pf) {
      WRITE_V((kt + 1) & 1)  // other buffer: safe before barrier
      __syncthreads();       // publishes V stores + K gll for tile kt+1
    }
  }

  // ---- epilogue: O^T -> [q][d] via LDS (reuse Ks) -> coalesced b128 stores ----
  __syncthreads();  // all waves done reading K/V
  bf16* Os = (bf16*)Ks + w * (16 * 72);
  float inv = 1.0f / lrow;
  #pragma unroll
  for (int fd = 0; fd < 4; ++fd) {
    bf16x4v ov;
    #pragma unroll
    for (int r = 0; r < 4; ++r) ov[r] = (bf16)(o[fd][r] * inv);
    *(bf16x4v*)(&Os[lq * 72 + fd * 16 + g * 4]) = ov;
  }
  asm volatile("" ::: "memory");
  #pragma unroll
  for (int p = 0; p < 2; ++p) {
    int idx = p * 64 + l;
    int row16 = idx >> 3, c8 = idx & 7;
    bf16x8 v = *(const bf16x8*)(&Os[row16 * 72 + c8 * 8]);
    *(bf16x8*)(&attn[(size_t)(b * 2048 + qrow0 + row16) * 1024 + h * 64 + c8 * 8]) = v;
  }
}

// ---------------- launch ----------------
extern "C" void kernel_launch(void* const* d_in, const int* in_sizes, int n_in,
                              void* d_out, int out_size, void* d_ws, size_t ws_size,
                              hipStream_t stream) {
  const float* x = (const float*)d_in[0];
  const int* pos = (const int*)d_in[1];
  const float* w_qkv = (const float*)d_in[2];
  const float* w_out = (const float*)d_in[3];
  float* out = (float*)d_out;

  char* ws = (char*)d_ws;
  bf16* xb   = (bf16*)(ws);
  bf16* wqb  = (bf16*)(ws + (8u << 20));
  bf16* wob  = (bf16*)(ws + (14u << 20));
  bf16* qkv  = (bf16*)(ws + (16u << 20));
  bf16* attn = (bf16*)(ws + (40u << 20));

  cast3_kernel<<<8192, 256, 0, stream>>>(x, w_qkv, w_out, xb, wqb, wob);

  dim3 g1(3072 / 128, 4096 / 128);
  gemm_bt<false, true><<<g1, 256, 0, stream>>>(xb, wqb, (void*)qkv, 4096, 3072, 1024, pos);

  dim3 gfa(32, 2048 / 64);  // x = bh (XCD pin), y = q-tile (reversed in kernel)
  fa_causal<<<gfa, 256, 0, stream>>>(qkv, attn);

  dim3 g2(1024 / 128, 4096 / 128);
  gemm_bt<true, false><<<g2, 256, 0, stream>>>(attn, wob, (void*)out, 4096, 1024, 1024, nullptr);
}